// Round 1
// baseline (949.690 us; speedup 1.0000x reference)
//
#include <hip/hip_runtime.h>

#define BB 8
#define CC 256
#define HH 128
#define WW 128
#define HW (HH*WW)

typedef float f32x4 __attribute__((ext_vector_type(4)));
typedef short s16x8 __attribute__((ext_vector_type(8)));

__device__ inline unsigned short f2bf(float f) {
  union { float f; unsigned int u; } un;
  un.f = f;
  unsigned int u = un.u;
  return (unsigned short)((u + 0x7fffu + ((u >> 16) & 1u)) >> 16);  // RNE
}

// ---------------- kernel 0: x NCHW f32 -> xbf NHWC bf16 ----------------
__global__ __launch_bounds__(256) void k_prepass(const float* __restrict__ x,
                                                 unsigned short* __restrict__ xbf) {
  __shared__ float tile[64][68];   // 68: row byte-stride 272 = 17*16, conflict-spread
  int bh = blockIdx.x;
  int b = bh >> 7, h = bh & 127;
  int w0 = blockIdx.y * 64;
  int c0 = blockIdx.z * 64;
  int t = threadIdx.x;
  {
    int c = t >> 2, wq = (t & 3) << 4;
    const float4* src = reinterpret_cast<const float4*>(
        x + (((size_t)(b * CC + c0 + c) * HH + h) * WW + w0 + wq));
    float4 v0 = src[0], v1 = src[1], v2 = src[2], v3 = src[3];
    *reinterpret_cast<float4*>(&tile[c][wq + 0])  = v0;
    *reinterpret_cast<float4*>(&tile[c][wq + 4])  = v1;
    *reinterpret_cast<float4*>(&tile[c][wq + 8])  = v2;
    *reinterpret_cast<float4*>(&tile[c][wq + 12]) = v3;
  }
  __syncthreads();
  {
    int w = t >> 2, cg = (t & 3) << 4;
    unsigned short tmp[16];
#pragma unroll
    for (int i = 0; i < 16; ++i) tmp[i] = f2bf(tile[cg + i][w]);
    unsigned short* dst = xbf + ((size_t)(b * HH + h) * WW + w0 + w) * CC + c0 + cg;
    *reinterpret_cast<int4*>(dst)     = *reinterpret_cast<int4*>(tmp);
    *reinterpret_cast<int4*>(dst + 8) = *reinterpret_cast<int4*>(tmp + 8);
  }
}

// ---------------- kernel 1: weight repack -> [chunk8][tap9][foc768][ci32] bf16 ----
__global__ __launch_bounds__(256) void k_repack(const float* __restrict__ Wq,
                                                const float* __restrict__ Wk,
                                                const float* __restrict__ Wv,
                                                unsigned short* __restrict__ Wp) {
  int idx = blockIdx.x * 256 + threadIdx.x;
  if (idx >= 8 * 9 * 768 * 32) return;
  int ci = idx & 31;
  int tmp = idx >> 5;
  int focs = tmp % 768;
  int tmp2 = tmp / 768;
  int tap = tmp2 % 9;
  int chunk = tmp2 / 9;
  int cv = focs >> 8, oc = focs & 255;
  int cin = chunk * 32 + ci;
  const float* Wsrc = (cv == 0) ? Wq : ((cv == 1) ? Wk : Wv);
  Wp[idx] = f2bf(Wsrc[(size_t)(oc * 256 + cin) * 9 + tap]);
}

// ---------------- kernel 2: fused QKV conv, implicit GEMM bf16 MFMA -----------
// grid (1024 = b*128+h, 6 = mtile of 128 fused-oc). block 256 = 4 waves (2x2).
#define PADC 40
__global__ __launch_bounds__(256) void k_conv(const unsigned short* __restrict__ xbf,
                                              const unsigned short* __restrict__ Wp,
                                              const float* __restrict__ bq,
                                              const float* __restrict__ bk,
                                              const float* __restrict__ bv,
                                              unsigned short* __restrict__ qkv) {
  __shared__ unsigned short xs[3][132][PADC];  // [row r][w+1 in 0..129][ci], pad 40
  __shared__ float bias_s[128];
  int bh = blockIdx.x;
  int b = bh >> 7, h = bh & 127;
  int mtile = blockIdx.y;
  int t = threadIdx.x;
  if (t < 128) {
    int focs = mtile * 128 + t;
    int cv = focs >> 8, oc = focs & 255;
    const float* bp = (cv == 0) ? bq : ((cv == 1) ? bk : bv);
    bias_s[t] = bp[oc];
  }
  int lane = t & 63, wave = t >> 6;
  int wm = wave >> 1, wn = wave & 1;
  int l15 = lane & 15, lg = lane >> 4;
  f32x4 acc[4][4] = {};
  for (int chunk = 0; chunk < 8; ++chunk) {
    __syncthreads();
    // stage 3 rows x 130 cols x 32 ci (bf16) from NHWC
    for (int g = t; g < 1560; g += 256) {
      int oct = g & 3;
      int wc = (g >> 2) % 130;
      int r = (g >> 2) / 130;
      int hin = h + r - 1, win = wc - 1;
      int4 val = {0, 0, 0, 0};
      if ((unsigned)hin < 128u && (unsigned)win < 128u) {
        val = *reinterpret_cast<const int4*>(
            xbf + ((size_t)(b * HH + hin) * WW + win) * CC + chunk * 32 + oct * 8);
      }
      *reinterpret_cast<int4*>(&xs[r][wc][oct * 8]) = val;
    }
    __syncthreads();
    const unsigned short* wpc = Wp + (size_t)chunk * (9 * 768 * 32)
                                + (size_t)(mtile * 128 + wm * 64 + l15) * 32 + lg * 8;
#pragma unroll
    for (int tap = 0; tap < 9; ++tap) {
      const int r = tap / 3, s = tap % 3;
      s16x8 bfr[4], afr[4];
#pragma unroll
      for (int n = 0; n < 4; ++n)
        bfr[n] = *reinterpret_cast<const s16x8*>(&xs[r][wn * 64 + n * 16 + l15 + s][lg * 8]);
      const unsigned short* ap = wpc + tap * (768 * 32);
#pragma unroll
      for (int m = 0; m < 4; ++m)
        afr[m] = *reinterpret_cast<const s16x8*>(ap + m * (16 * 32));
#pragma unroll
      for (int m = 0; m < 4; ++m)
#pragma unroll
        for (int n = 0; n < 4; ++n)
          acc[m][n] = __builtin_amdgcn_mfma_f32_16x16x32_bf16(afr[m], bfr[n], acc[m][n], 0, 0, 0);
    }
  }
  // epilogue: bias, relu (q,k only), store bf16 to qkv[conv][b][oc][h][w]
#pragma unroll
  for (int m = 0; m < 4; ++m) {
#pragma unroll
    for (int n = 0; n < 4; ++n) {
      int wcol = wn * 64 + n * 16 + l15;
#pragma unroll
      for (int rg = 0; rg < 4; ++rg) {
        int rl = wm * 64 + m * 16 + lg * 4 + rg;   // verified D-layout
        float v = acc[m][n][rg] + bias_s[rl];
        int focs = mtile * 128 + rl;
        if (focs < 512) v = fmaxf(v, 0.0f);        // relu for q,k
        int cv = focs >> 8, oc = focs & 255;
        qkv[(size_t)(cv * 2048 + b * 256 + oc) * HW + h * WW + wcol] = f2bf(v);
      }
    }
  }
}

// ---------------- kernel 3: per-(b,c) attention -------------------------------
// S = q@k (128x128), global softmax over all 16384, out = A@v + x
#define PADA 136
__global__ __launch_bounds__(256) void k_attn(const unsigned short* __restrict__ qkv,
                                              const float* __restrict__ x,
                                              float* __restrict__ out) {
  __shared__ unsigned short al[128][PADA];  // softmaxed A (bf16)
  __shared__ unsigned short kt[128][PADA];  // k transposed: kt[w'][h]
  __shared__ unsigned short vt[128][PADA];  // v transposed: vt[w'][h]
  __shared__ float red[8];
  int bc = blockIdx.x;
  const unsigned short* qp = qkv + (size_t)bc * HW;
  const unsigned short* kp = qkv + (size_t)(2048 + bc) * HW;
  const unsigned short* vp = qkv + (size_t)(4096 + bc) * HW;
  int t = threadIdx.x;
  for (int g = t; g < HW; g += 256) {
    int row = g >> 7, col = g & 127;
    kt[col][row] = kp[g];
    vt[col][row] = vp[g];
  }
  __syncthreads();
  int lane = t & 63, wave = t >> 6;
  int wm = wave >> 1, wn = wave & 1;
  int l15 = lane & 15, lg = lane >> 4;
  f32x4 acc[4][4] = {};
#pragma unroll
  for (int kk = 0; kk < 4; ++kk) {
    s16x8 af[4], bfr[4];
#pragma unroll
    for (int m = 0; m < 4; ++m)
      af[m] = *reinterpret_cast<const s16x8*>(qp + (size_t)(wm * 64 + m * 16 + l15) * WW + kk * 32 + lg * 8);
#pragma unroll
    for (int n = 0; n < 4; ++n)
      bfr[n] = *reinterpret_cast<const s16x8*>(&kt[wn * 64 + n * 16 + l15][kk * 32 + lg * 8]);
#pragma unroll
    for (int m = 0; m < 4; ++m)
#pragma unroll
      for (int n = 0; n < 4; ++n)
        acc[m][n] = __builtin_amdgcn_mfma_f32_16x16x32_bf16(af[m], bfr[n], acc[m][n], 0, 0, 0);
  }
  // global softmax over all 16384 entries of S
  float lm = -3.0e38f;
#pragma unroll
  for (int m = 0; m < 4; ++m)
#pragma unroll
    for (int n = 0; n < 4; ++n)
#pragma unroll
      for (int rg = 0; rg < 4; ++rg)
        lm = fmaxf(lm, acc[m][n][rg]);
  for (int off = 32; off > 0; off >>= 1) lm = fmaxf(lm, __shfl_xor(lm, off));
  if (lane == 0) red[wave] = lm;
  __syncthreads();
  float M = fmaxf(fmaxf(red[0], red[1]), fmaxf(red[2], red[3]));
  float ls = 0.0f;
#pragma unroll
  for (int m = 0; m < 4; ++m)
#pragma unroll
    for (int n = 0; n < 4; ++n)
#pragma unroll
      for (int rg = 0; rg < 4; ++rg)
        ls += __expf(acc[m][n][rg] - M);
  for (int off = 32; off > 0; off >>= 1) ls += __shfl_xor(ls, off);
  if (lane == 0) red[4 + wave] = ls;
  __syncthreads();
  float inv = 1.0f / (red[4] + red[5] + red[6] + red[7]);
#pragma unroll
  for (int m = 0; m < 4; ++m) {
#pragma unroll
    for (int n = 0; n < 4; ++n) {
      int col = wn * 64 + n * 16 + l15;
#pragma unroll
      for (int rg = 0; rg < 4; ++rg) {
        int row = wm * 64 + m * 16 + lg * 4 + rg;
        al[row][col] = f2bf(__expf(acc[m][n][rg] - M) * inv);
      }
    }
  }
  __syncthreads();
  f32x4 o_[4][4] = {};
#pragma unroll
  for (int kk = 0; kk < 4; ++kk) {
    s16x8 af[4], bfr[4];
#pragma unroll
    for (int m = 0; m < 4; ++m)
      af[m] = *reinterpret_cast<const s16x8*>(&al[wm * 64 + m * 16 + l15][kk * 32 + lg * 8]);
#pragma unroll
    for (int n = 0; n < 4; ++n)
      bfr[n] = *reinterpret_cast<const s16x8*>(&vt[wn * 64 + n * 16 + l15][kk * 32 + lg * 8]);
#pragma unroll
    for (int m = 0; m < 4; ++m)
#pragma unroll
      for (int n = 0; n < 4; ++n)
        o_[m][n] = __builtin_amdgcn_mfma_f32_16x16x32_bf16(af[m], bfr[n], o_[m][n], 0, 0, 0);
  }
  const float* xp = x + (size_t)bc * HW;
  float* op = out + (size_t)bc * HW;
#pragma unroll
  for (int m = 0; m < 4; ++m) {
#pragma unroll
    for (int n = 0; n < 4; ++n) {
      int col = wn * 64 + n * 16 + l15;
#pragma unroll
      for (int rg = 0; rg < 4; ++rg) {
        int row = wm * 64 + m * 16 + lg * 4 + rg;
        op[row * WW + col] = o_[m][n][rg] + xp[row * WW + col];
      }
    }
  }
}

extern "C" void kernel_launch(void* const* d_in, const int* in_sizes, int n_in,
                              void* d_out, int out_size, void* d_ws, size_t ws_size,
                              hipStream_t stream) {
  const float* x  = (const float*)d_in[0];
  const float* Wq = (const float*)d_in[1];
  const float* bq = (const float*)d_in[2];
  const float* Wk = (const float*)d_in[3];
  const float* bk = (const float*)d_in[4];
  const float* Wv = (const float*)d_in[5];
  const float* bv = (const float*)d_in[6];
  float* out = (float*)d_out;

  // workspace layout (ushort elements): xbf 33.5M | qkv 100.7M | Wp 1.77M
  unsigned short* xbf = (unsigned short*)d_ws;
  unsigned short* qkv = xbf + (size_t)33554432;
  unsigned short* Wp  = qkv + (size_t)3 * 33554432;

  dim3 g0(1024, 2, 4);
  k_prepass<<<g0, 256, 0, stream>>>(x, xbf);
  k_repack<<<6912, 256, 0, stream>>>(Wq, Wk, Wv, Wp);
  dim3 g2(1024, 6);
  k_conv<<<g2, 256, 0, stream>>>(xbf, Wp, bq, bk, bv, qkv);
  k_attn<<<2048, 256, 0, stream>>>(qkv, x, out);
}

// Round 2
// 583.242 us; speedup vs baseline: 1.6283x; 1.6283x over previous
//
#include <hip/hip_runtime.h>

#define BB 8
#define CC 256
#define HH 128
#define WW 128
#define HW (HH*WW)

typedef float f32x4 __attribute__((ext_vector_type(4)));
typedef short s16x8 __attribute__((ext_vector_type(8)));

__device__ inline unsigned short f2bf(float f) {
  union { float f; unsigned int u; } un;
  un.f = f;
  unsigned int u = un.u;
  return (unsigned short)((u + 0x7fffu + ((u >> 16) & 1u)) >> 16);  // RNE
}

// ---------------- kernel 0: x NCHW f32 -> xbf NHWC bf16 ----------------
__global__ __launch_bounds__(256) void k_prepass(const float* __restrict__ x,
                                                 unsigned short* __restrict__ xbf) {
  __shared__ float tile[64][68];
  int bh = blockIdx.x;
  int b = bh >> 7, h = bh & 127;
  int w0 = blockIdx.y * 64;
  int c0 = blockIdx.z * 64;
  int t = threadIdx.x;
  {
    int c = t >> 2, wq = (t & 3) << 4;
    const float4* src = reinterpret_cast<const float4*>(
        x + (((size_t)(b * CC + c0 + c) * HH + h) * WW + w0 + wq));
    float4 v0 = src[0], v1 = src[1], v2 = src[2], v3 = src[3];
    *reinterpret_cast<float4*>(&tile[c][wq + 0])  = v0;
    *reinterpret_cast<float4*>(&tile[c][wq + 4])  = v1;
    *reinterpret_cast<float4*>(&tile[c][wq + 8])  = v2;
    *reinterpret_cast<float4*>(&tile[c][wq + 12]) = v3;
  }
  __syncthreads();
  {
    int w = t >> 2, cg = (t & 3) << 4;
    unsigned short tmp[16];
#pragma unroll
    for (int i = 0; i < 16; ++i) tmp[i] = f2bf(tile[cg + i][w]);
    unsigned short* dst = xbf + ((size_t)(b * HH + h) * WW + w0 + w) * CC + c0 + cg;
    *reinterpret_cast<int4*>(dst)     = *reinterpret_cast<int4*>(tmp);
    *reinterpret_cast<int4*>(dst + 8) = *reinterpret_cast<int4*>(tmp + 8);
  }
}

// ---------------- kernel 1: weight repack -> [chunk8][tap9][foc768][ci32] bf16 ----
__global__ __launch_bounds__(256) void k_repack(const float* __restrict__ Wq,
                                                const float* __restrict__ Wk,
                                                const float* __restrict__ Wv,
                                                unsigned short* __restrict__ Wp) {
  int idx = blockIdx.x * 256 + threadIdx.x;
  if (idx >= 8 * 9 * 768 * 32) return;
  int ci = idx & 31;
  int tmp = idx >> 5;
  int focs = tmp % 768;
  int tmp2 = tmp / 768;
  int tap = tmp2 % 9;
  int chunk = tmp2 / 9;
  int cv = focs >> 8, oc = focs & 255;
  int cin = chunk * 32 + ci;
  const float* Wsrc = (cv == 0) ? Wq : ((cv == 1) ? Wk : Wv);
  Wp[idx] = f2bf(Wsrc[(size_t)(oc * 256 + cin) * 9 + tap]);
}

// ---------------- kernel 2: fused QKV conv, implicit GEMM bf16 MFMA -----------
// Flat grid 3072 = 8 XCD-chunks x 384. Per XCD: one batch image, mtile fast.
// Block: 128 focs x (2 h-rows x 128 w). 4 waves (wm = focs half, wn = h row).
#define PADC 40
__global__ __launch_bounds__(256, 2) void k_conv(const unsigned short* __restrict__ xbf,
                                                 const unsigned short* __restrict__ Wp,
                                                 const float* __restrict__ bq,
                                                 const float* __restrict__ bk,
                                                 const float* __restrict__ bv,
                                                 unsigned short* __restrict__ qkv) {
  __shared__ unsigned short xs[4][132][PADC];  // rows h0-1..h0+2, wc 0..129, 32 ci
  __shared__ float bias_s[128];
  int bid = blockIdx.x;
  int v_ = (bid & 7) * 384 + (bid >> 3);   // bijective XCD swizzle (3072 % 8 == 0)
  int mtile = v_ % 6;
  int bhp = v_ / 6;                        // 0..511
  int b = bhp >> 6;
  int h0 = (bhp & 63) * 2;
  int t = threadIdx.x;
  if (t < 128) {
    int focs = mtile * 128 + t;
    int cv = focs >> 8, oc = focs & 255;
    const float* bp = (cv == 0) ? bq : ((cv == 1) ? bk : bv);
    bias_s[t] = bp[oc];
  }
  int lane = t & 63, wave = t >> 6;
  int wm = wave >> 1, wn = wave & 1;
  int l15 = lane & 15, lg = lane >> 4;
  f32x4 acc[4][8] = {};
  for (int chunk = 0; chunk < 8; ++chunk) {
    __syncthreads();
    // stage 4 rows x 130 cols x 32 ci (bf16) from NHWC; 2080 16B loads
    for (int g = t; g < 2080; g += 256) {
      int oct = g & 3;
      int wc = (g >> 2) % 130;
      int r = (g >> 2) / 130;
      int hin = h0 + r - 1, win = wc - 1;
      int4 val = {0, 0, 0, 0};
      if ((unsigned)hin < 128u && (unsigned)win < 128u) {
        val = *reinterpret_cast<const int4*>(
            xbf + ((size_t)(b * HH + hin) * WW + win) * CC + chunk * 32 + oct * 8);
      }
      *reinterpret_cast<int4*>(&xs[r][wc][oct * 8]) = val;
    }
    __syncthreads();
    const unsigned short* wpc = Wp + (size_t)chunk * (9 * 768 * 32)
                                + (size_t)(mtile * 128 + wm * 64 + l15) * 32 + lg * 8;
#pragma unroll
    for (int tap = 0; tap < 9; ++tap) {
      const int r = tap / 3, s = tap % 3;
      s16x8 afr[4], bfr[8];
      const unsigned short* ap = wpc + tap * (768 * 32);
#pragma unroll
      for (int m = 0; m < 4; ++m)
        afr[m] = *reinterpret_cast<const s16x8*>(ap + m * (16 * 32));
#pragma unroll
      for (int n = 0; n < 8; ++n)
        bfr[n] = *reinterpret_cast<const s16x8*>(&xs[wn + r][n * 16 + l15 + s][lg * 8]);
#pragma unroll
      for (int m = 0; m < 4; ++m)
#pragma unroll
        for (int n = 0; n < 8; ++n)
          acc[m][n] = __builtin_amdgcn_mfma_f32_16x16x32_bf16(afr[m], bfr[n], acc[m][n], 0, 0, 0);
    }
  }
  // epilogue: bias, relu (q,k only), store bf16 to qkv[conv][b][oc][h][w]
#pragma unroll
  for (int m = 0; m < 4; ++m) {
#pragma unroll
    for (int n = 0; n < 8; ++n) {
      int wcol = n * 16 + l15;
      int h = h0 + wn;
#pragma unroll
      for (int rg = 0; rg < 4; ++rg) {
        int rl = wm * 64 + m * 16 + lg * 4 + rg;   // verified D-layout
        float vv = acc[m][n][rg] + bias_s[rl];
        int focs = mtile * 128 + rl;
        if (focs < 512) vv = fmaxf(vv, 0.0f);      // relu for q,k
        int cv = focs >> 8, oc = focs & 255;
        qkv[(size_t)(cv * 2048 + b * 256 + oc) * HW + h * WW + wcol] = f2bf(vv);
      }
    }
  }
}

// ---------------- kernel 3: per-(b,c) attention -------------------------------
#define PADA 136
__global__ __launch_bounds__(256) void k_attn(const unsigned short* __restrict__ qkv,
                                              const float* __restrict__ x,
                                              float* __restrict__ out) {
  __shared__ unsigned short al[128][PADA];
  __shared__ unsigned short kt[128][PADA];
  __shared__ unsigned short vt[128][PADA];
  __shared__ float red[8];
  int bc = blockIdx.x;
  const unsigned short* qp = qkv + (size_t)bc * HW;
  const unsigned short* kp = qkv + (size_t)(2048 + bc) * HW;
  const unsigned short* vp = qkv + (size_t)(4096 + bc) * HW;
  int t = threadIdx.x;
  for (int g = t; g < HW; g += 256) {
    int row = g >> 7, col = g & 127;
    kt[col][row] = kp[g];
    vt[col][row] = vp[g];
  }
  __syncthreads();
  int lane = t & 63, wave = t >> 6;
  int wm = wave >> 1, wn = wave & 1;
  int l15 = lane & 15, lg = lane >> 4;
  f32x4 acc[4][4] = {};
#pragma unroll
  for (int kk = 0; kk < 4; ++kk) {
    s16x8 af[4], bfr[4];
#pragma unroll
    for (int m = 0; m < 4; ++m)
      af[m] = *reinterpret_cast<const s16x8*>(qp + (size_t)(wm * 64 + m * 16 + l15) * WW + kk * 32 + lg * 8);
#pragma unroll
    for (int n = 0; n < 4; ++n)
      bfr[n] = *reinterpret_cast<const s16x8*>(&kt[wn * 64 + n * 16 + l15][kk * 32 + lg * 8]);
#pragma unroll
    for (int m = 0; m < 4; ++m)
#pragma unroll
      for (int n = 0; n < 4; ++n)
        acc[m][n] = __builtin_amdgcn_mfma_f32_16x16x32_bf16(af[m], bfr[n], acc[m][n], 0, 0, 0);
  }
  float lm = -3.0e38f;
#pragma unroll
  for (int m = 0; m < 4; ++m)
#pragma unroll
    for (int n = 0; n < 4; ++n)
#pragma unroll
      for (int rg = 0; rg < 4; ++rg)
        lm = fmaxf(lm, acc[m][n][rg]);
  for (int off = 32; off > 0; off >>= 1) lm = fmaxf(lm, __shfl_xor(lm, off));
  if (lane == 0) red[wave] = lm;
  __syncthreads();
  float M = fmaxf(fmaxf(red[0], red[1]), fmaxf(red[2], red[3]));
  float ls = 0.0f;
#pragma unroll
  for (int m = 0; m < 4; ++m)
#pragma unroll
    for (int n = 0; n < 4; ++n)
#pragma unroll
      for (int rg = 0; rg < 4; ++rg)
        ls += __expf(acc[m][n][rg] - M);
  for (int off = 32; off > 0; off >>= 1) ls += __shfl_xor(ls, off);
  if (lane == 0) red[4 + wave] = ls;
  __syncthreads();
  float inv = 1.0f / (red[4] + red[5] + red[6] + red[7]);
#pragma unroll
  for (int m = 0; m < 4; ++m) {
#pragma unroll
    for (int n = 0; n < 4; ++n) {
      int col = wn * 64 + n * 16 + l15;
#pragma unroll
      for (int rg = 0; rg < 4; ++rg) {
        int row = wm * 64 + m * 16 + lg * 4 + rg;
        al[row][col] = f2bf(__expf(acc[m][n][rg] - M) * inv);
      }
    }
  }
  __syncthreads();
  f32x4 o_[4][4] = {};
#pragma unroll
  for (int kk = 0; kk < 4; ++kk) {
    s16x8 af[4], bfr[4];
#pragma unroll
    for (int m = 0; m < 4; ++m)
      af[m] = *reinterpret_cast<const s16x8*>(&al[wm * 64 + m * 16 + l15][kk * 32 + lg * 8]);
#pragma unroll
    for (int n = 0; n < 4; ++n)
      bfr[n] = *reinterpret_cast<const s16x8*>(&vt[wn * 64 + n * 16 + l15][kk * 32 + lg * 8]);
#pragma unroll
    for (int m = 0; m < 4; ++m)
#pragma unroll
      for (int n = 0; n < 4; ++n)
        o_[m][n] = __builtin_amdgcn_mfma_f32_16x16x32_bf16(af[m], bfr[n], o_[m][n], 0, 0, 0);
  }
  const float* xp = x + (size_t)bc * HW;
  float* op = out + (size_t)bc * HW;
#pragma unroll
  for (int m = 0; m < 4; ++m) {
#pragma unroll
    for (int n = 0; n < 4; ++n) {
      int col = wn * 64 + n * 16 + l15;
#pragma unroll
      for (int rg = 0; rg < 4; ++rg) {
        int row = wm * 64 + m * 16 + lg * 4 + rg;
        op[row * WW + col] = o_[m][n][rg] + xp[row * WW + col];
      }
    }
  }
}

extern "C" void kernel_launch(void* const* d_in, const int* in_sizes, int n_in,
                              void* d_out, int out_size, void* d_ws, size_t ws_size,
                              hipStream_t stream) {
  const float* x  = (const float*)d_in[0];
  const float* Wq = (const float*)d_in[1];
  const float* bq = (const float*)d_in[2];
  const float* Wk = (const float*)d_in[3];
  const float* bk = (const float*)d_in[4];
  const float* Wv = (const float*)d_in[5];
  const float* bv = (const float*)d_in[6];
  float* out = (float*)d_out;

  unsigned short* xbf = (unsigned short*)d_ws;
  unsigned short* qkv = xbf + (size_t)33554432;
  unsigned short* Wp  = qkv + (size_t)3 * 33554432;

  dim3 g0(1024, 2, 4);
  k_prepass<<<g0, 256, 0, stream>>>(x, xbf);
  k_repack<<<6912, 256, 0, stream>>>(Wq, Wk, Wv, Wp);
  k_conv<<<3072, 256, 0, stream>>>(xbf, Wp, bq, bk, bv, qkv);
  k_attn<<<2048, 256, 0, stream>>>(qkv, x, out);
}

// Round 3
// 575.508 us; speedup vs baseline: 1.6502x; 1.0134x over previous
//
#include <hip/hip_runtime.h>

#define BB 8
#define CC 256
#define HH 128
#define WW 128
#define HW (HH*WW)

typedef float f32x4 __attribute__((ext_vector_type(4)));
typedef float f32x16 __attribute__((ext_vector_type(16)));
typedef short s16x8 __attribute__((ext_vector_type(8)));

__device__ inline unsigned short f2bf(float f) {
  union { float f; unsigned int u; } un;
  un.f = f;
  unsigned int u = un.u;
  return (unsigned short)((u + 0x7fffu + ((u >> 16) & 1u)) >> 16);  // RNE
}

__device__ __forceinline__ void gload_lds16(const void* g, void* l) {
  __builtin_amdgcn_global_load_lds(
      (const __attribute__((address_space(1))) unsigned int*)g,
      (__attribute__((address_space(3))) unsigned int*)l, 16, 0, 0);
}

// ---------------- kernel 0: x NCHW f32 -> xbf NHWC bf16 ----------------
__global__ __launch_bounds__(256) void k_prepass(const float* __restrict__ x,
                                                 unsigned short* __restrict__ xbf) {
  __shared__ float tile[64][68];
  int bh = blockIdx.x;
  int b = bh >> 7, h = bh & 127;
  int w0 = blockIdx.y * 64;
  int c0 = blockIdx.z * 64;
  int t = threadIdx.x;
  {
    int c = t >> 2, wq = (t & 3) << 4;
    const float4* src = reinterpret_cast<const float4*>(
        x + (((size_t)(b * CC + c0 + c) * HH + h) * WW + w0 + wq));
    float4 v0 = src[0], v1 = src[1], v2 = src[2], v3 = src[3];
    *reinterpret_cast<float4*>(&tile[c][wq + 0])  = v0;
    *reinterpret_cast<float4*>(&tile[c][wq + 4])  = v1;
    *reinterpret_cast<float4*>(&tile[c][wq + 8])  = v2;
    *reinterpret_cast<float4*>(&tile[c][wq + 12]) = v3;
  }
  __syncthreads();
  {
    int w = t >> 2, cg = (t & 3) << 4;
    unsigned short tmp[16];
#pragma unroll
    for (int i = 0; i < 16; ++i) tmp[i] = f2bf(tile[cg + i][w]);
    unsigned short* dst = xbf + ((size_t)(b * HH + h) * WW + w0 + w) * CC + c0 + cg;
    *reinterpret_cast<int4*>(dst)     = *reinterpret_cast<int4*>(tmp);
    *reinterpret_cast<int4*>(dst + 8) = *reinterpret_cast<int4*>(tmp + 8);
  }
}

// ------- kernel 1: weight repack -> [chunk8][tap9][foc768][ci32] bf16 + zeropage ----
__global__ __launch_bounds__(256) void k_repack(const float* __restrict__ Wq,
                                                const float* __restrict__ Wk,
                                                const float* __restrict__ Wv,
                                                unsigned short* __restrict__ Wp,
                                                unsigned short* __restrict__ zp) {
  if (blockIdx.x == 0 && threadIdx.x < 64) {
    int4 z = {0, 0, 0, 0};
    reinterpret_cast<int4*>(zp)[threadIdx.x] = z;   // 1 KB zero page
  }
  int idx = blockIdx.x * 256 + threadIdx.x;
  if (idx >= 8 * 9 * 768 * 32) return;
  int ci = idx & 31;
  int tmp = idx >> 5;
  int focs = tmp % 768;
  int tmp2 = tmp / 768;
  int tap = tmp2 % 9;
  int chunk = tmp2 / 9;
  int cv = focs >> 8, oc = focs & 255;
  int cin = chunk * 32 + ci;
  const float* Wsrc = (cv == 0) ? Wq : ((cv == 1) ? Wk : Wv);
  Wp[idx] = f2bf(Wsrc[(size_t)(oc * 256 + cin) * 9 + tap]);
}

// ---------------- kernel 2: fused QKV conv, 32x32x16 MFMA, async 2-phase ------
// Block: 128 focs x 2 h-rows x 128 w. 4 waves: (wm = m-half, wq = n-half),
// each wave computes 2 m-tiles x 2 rows x 2 n-tiles of 32x32.
// LDS x-tile linear [4 rows][132 wc][32 ci] per buffer, oct-slot XOR swizzle
// (slot = oct ^ ((wc>>1)&3)) applied on the *global source* at staging and on
// ds_read addresses (both-sides rule); wc=0/129 are permanent zero halo cells.
__global__ __launch_bounds__(256, 2) void k_conv(const unsigned short* __restrict__ xbf,
                                                 const unsigned short* __restrict__ Wp,
                                                 const unsigned short* __restrict__ zp,
                                                 const float* __restrict__ bq,
                                                 const float* __restrict__ bk,
                                                 const float* __restrict__ bv,
                                                 unsigned short* __restrict__ qkv) {
  __shared__ unsigned short xs[2][4][132][32];
  __shared__ float bias_s[128];
  int bid = blockIdx.x;
  int v_ = (bid & 7) * 384 + (bid >> 3);   // bijective XCD swizzle
  int mtile = v_ % 6;
  int bhp = v_ / 6;
  int b = bhp >> 6;
  int h0 = (bhp & 63) * 2;
  int t = threadIdx.x;
  int lane = t & 63, wave = t >> 6;
  int wm = wave >> 1, wq = wave & 1;
  int l31 = lane & 31, lg1 = lane >> 5;

  if (t < 128) {
    int focs = mtile * 128 + t;
    int cv = focs >> 8, oc = focs & 255;
    const float* bp = (cv == 0) ? bq : ((cv == 1) ? bk : bv);
    bias_s[t] = bp[oc];
  }
  {  // zero the w-halo cells (wc = 0 and 129) of both buffers, all 4 rows
    int cell = t >> 4;
    int bf_ = cell >> 3, r_ = (cell >> 1) & 3;
    int wc_ = (cell & 1) ? 129 : 0;
    *reinterpret_cast<int*>(reinterpret_cast<char*>(&xs[bf_][r_][wc_][0]) + (t & 15) * 4) = 0;
  }

  // ---- staging setup: wave w stages input row r = w (hin = h0 + r - 1)
  int l2 = lane >> 2, l4 = lane & 3;
  int osw = l4 ^ (((l2 + 1) >> 1) & 3);    // swizzled logical oct for this lane
  int rsta = wave;
  int hin = h0 + rsta - 1;
  bool inb = ((unsigned)hin < 128u);
  const unsigned short* srow =
      xbf + ((size_t)(b * HH + (inb ? hin : 0)) * WW + l2) * CC + osw * 8;
  const unsigned short* zsrc = zp + lane * 8;

  auto STAGE = [&](int bufn, int chunk) {
    char* d0 = reinterpret_cast<char*>(&xs[bufn][rsta][1][0]);
    if (inb) {
      const unsigned short* s0 = srow + chunk * 32;
#pragma unroll
      for (int j = 0; j < 8; ++j)
        gload_lds16(s0 + j * (16 * CC), d0 + j * 1024);
    } else {
#pragma unroll
      for (int j = 0; j < 8; ++j)
        gload_lds16(zsrc, d0 + j * 1024);
    }
  };

  f32x16 acc[2][2][2] = {};   // [mt][row][nt]
  STAGE(0, 0);
  __syncthreads();
  int buf = 0;
  for (int chunk = 0; chunk < 8; ++chunk) {
    if (chunk < 7) STAGE(buf ^ 1, chunk + 1);
    const unsigned short (*xsb)[132][32] = xs[buf];
    const unsigned short* ap0 = Wp + (size_t)chunk * (9 * 768 * 32)
        + (size_t)(mtile * 128 + wm * 64 + l31) * 32 + lg1 * 8;
#pragma unroll
    for (int ss = 0; ss < 3; ++ss) {
#pragma unroll
      for (int kk = 0; kk < 2; ++kk) {
        s16x8 Bf[4][2];   // [rin][nt]
#pragma unroll
        for (int rin = 0; rin < 4; ++rin)
#pragma unroll
        for (int nt = 0; nt < 2; ++nt) {
          int wc = wq * 64 + nt * 32 + l31 + ss;
          int pslot = (kk * 2 + lg1) ^ ((wc >> 1) & 3);
          Bf[rin][nt] = *reinterpret_cast<const s16x8*>(
              reinterpret_cast<const char*>(&xsb[rin][0][0]) + wc * 64 + pslot * 16);
        }
        s16x8 Af[3][2];   // [rr][mt]
#pragma unroll
        for (int rr = 0; rr < 3; ++rr)
#pragma unroll
        for (int mt = 0; mt < 2; ++mt)
          Af[rr][mt] = *reinterpret_cast<const s16x8*>(
              ap0 + (rr * 3 + ss) * (768 * 32) + mt * 1024 + kk * 16);
#pragma unroll
        for (int rr = 0; rr < 3; ++rr)
#pragma unroll
        for (int row = 0; row < 2; ++row)
#pragma unroll
        for (int mt = 0; mt < 2; ++mt)
#pragma unroll
        for (int nt = 0; nt < 2; ++nt)
          acc[mt][row][nt] = __builtin_amdgcn_mfma_f32_32x32x16_bf16(
              Af[rr][mt], Bf[row + rr][nt], acc[mt][row][nt], 0, 0, 0);
      }
    }
    if (chunk < 7) __syncthreads();
    buf ^= 1;
  }

  // epilogue: bias, relu (q,k), store bf16. D-layout 32x32:
  // col = lane&31, row = (reg&3) + 8*(reg>>2) + 4*(lane>>5)
#pragma unroll
  for (int mt = 0; mt < 2; ++mt) {
#pragma unroll
    for (int row = 0; row < 2; ++row) {
#pragma unroll
      for (int nt = 0; nt < 2; ++nt) {
        int wcol = wq * 64 + nt * 32 + l31;
        int h = h0 + row;
#pragma unroll
        for (int reg = 0; reg < 16; ++reg) {
          int rloc = (reg & 3) + 8 * (reg >> 2) + 4 * lg1;
          int floc = wm * 64 + mt * 32 + rloc;
          float vv = acc[mt][row][nt][reg] + bias_s[floc];
          int focs = mtile * 128 + floc;
          if (focs < 512) vv = fmaxf(vv, 0.0f);
          int cv = focs >> 8, oc = focs & 255;
          qkv[(size_t)(cv * 2048 + b * 256 + oc) * HW + h * WW + wcol] = f2bf(vv);
        }
      }
    }
  }
}

// ---------------- kernel 3: per-(b,c) attention -------------------------------
#define PADA 136
__global__ __launch_bounds__(256) void k_attn(const unsigned short* __restrict__ qkv,
                                              const float* __restrict__ x,
                                              float* __restrict__ out) {
  __shared__ unsigned short al[128][PADA];
  __shared__ unsigned short kt[128][PADA];
  __shared__ unsigned short vt[128][PADA];
  __shared__ float red[8];
  int bc = blockIdx.x;
  const unsigned short* qp = qkv + (size_t)bc * HW;
  const unsigned short* kp = qkv + (size_t)(2048 + bc) * HW;
  const unsigned short* vp = qkv + (size_t)(4096 + bc) * HW;
  int t = threadIdx.x;
  for (int g = t; g < HW; g += 256) {
    int row = g >> 7, col = g & 127;
    kt[col][row] = kp[g];
    vt[col][row] = vp[g];
  }
  __syncthreads();
  int lane = t & 63, wave = t >> 6;
  int wm = wave >> 1, wn = wave & 1;
  int l15 = lane & 15, lg = lane >> 4;
  f32x4 acc[4][4] = {};
#pragma unroll
  for (int kk = 0; kk < 4; ++kk) {
    s16x8 af[4], bfr[4];
#pragma unroll
    for (int m = 0; m < 4; ++m)
      af[m] = *reinterpret_cast<const s16x8*>(qp + (size_t)(wm * 64 + m * 16 + l15) * WW + kk * 32 + lg * 8);
#pragma unroll
    for (int n = 0; n < 4; ++n)
      bfr[n] = *reinterpret_cast<const s16x8*>(&kt[wn * 64 + n * 16 + l15][kk * 32 + lg * 8]);
#pragma unroll
    for (int m = 0; m < 4; ++m)
#pragma unroll
      for (int n = 0; n < 4; ++n)
        acc[m][n] = __builtin_amdgcn_mfma_f32_16x16x32_bf16(af[m], bfr[n], acc[m][n], 0, 0, 0);
  }
  float lm = -3.0e38f;
#pragma unroll
  for (int m = 0; m < 4; ++m)
#pragma unroll
    for (int n = 0; n < 4; ++n)
#pragma unroll
      for (int rg = 0; rg < 4; ++rg)
        lm = fmaxf(lm, acc[m][n][rg]);
  for (int off = 32; off > 0; off >>= 1) lm = fmaxf(lm, __shfl_xor(lm, off));
  if (lane == 0) red[wave] = lm;
  __syncthreads();
  float M = fmaxf(fmaxf(red[0], red[1]), fmaxf(red[2], red[3]));
  float ls = 0.0f;
#pragma unroll
  for (int m = 0; m < 4; ++m)
#pragma unroll
    for (int n = 0; n < 4; ++n)
#pragma unroll
      for (int rg = 0; rg < 4; ++rg)
        ls += __expf(acc[m][n][rg] - M);
  for (int off = 32; off > 0; off >>= 1) ls += __shfl_xor(ls, off);
  if (lane == 0) red[4 + wave] = ls;
  __syncthreads();
  float inv = 1.0f / (red[4] + red[5] + red[6] + red[7]);
#pragma unroll
  for (int m = 0; m < 4; ++m) {
#pragma unroll
    for (int n = 0; n < 4; ++n) {
      int col = wn * 64 + n * 16 + l15;
#pragma unroll
      for (int rg = 0; rg < 4; ++rg) {
        int row = wm * 64 + m * 16 + lg * 4 + rg;
        al[row][col] = f2bf(__expf(acc[m][n][rg] - M) * inv);
      }
    }
  }
  __syncthreads();
  f32x4 o_[4][4] = {};
#pragma unroll
  for (int kk = 0; kk < 4; ++kk) {
    s16x8 af[4], bfr[4];
#pragma unroll
    for (int m = 0; m < 4; ++m)
      af[m] = *reinterpret_cast<const s16x8*>(&al[wm * 64 + m * 16 + l15][kk * 32 + lg * 8]);
#pragma unroll
    for (int n = 0; n < 4; ++n)
      bfr[n] = *reinterpret_cast<const s16x8*>(&vt[wn * 64 + n * 16 + l15][kk * 32 + lg * 8]);
#pragma unroll
    for (int m = 0; m < 4; ++m)
#pragma unroll
      for (int n = 0; n < 4; ++n)
        o_[m][n] = __builtin_amdgcn_mfma_f32_16x16x32_bf16(af[m], bfr[n], o_[m][n], 0, 0, 0);
  }
  const float* xp = x + (size_t)bc * HW;
  float* op = out + (size_t)bc * HW;
#pragma unroll
  for (int m = 0; m < 4; ++m) {
#pragma unroll
    for (int n = 0; n < 4; ++n) {
      int col = wn * 64 + n * 16 + l15;
#pragma unroll
      for (int rg = 0; rg < 4; ++rg) {
        int row = wm * 64 + m * 16 + lg * 4 + rg;
        op[row * WW + col] = o_[m][n][rg] + xp[row * WW + col];
      }
    }
  }
}

extern "C" void kernel_launch(void* const* d_in, const int* in_sizes, int n_in,
                              void* d_out, int out_size, void* d_ws, size_t ws_size,
                              hipStream_t stream) {
  const float* x  = (const float*)d_in[0];
  const float* Wq = (const float*)d_in[1];
  const float* bq = (const float*)d_in[2];
  const float* Wk = (const float*)d_in[3];
  const float* bk = (const float*)d_in[4];
  const float* Wv = (const float*)d_in[5];
  const float* bv = (const float*)d_in[6];
  float* out = (float*)d_out;

  unsigned short* xbf = (unsigned short*)d_ws;
  unsigned short* qkv = xbf + (size_t)33554432;
  unsigned short* Wp  = qkv + (size_t)3 * 33554432;
  unsigned short* zp  = Wp + (size_t)(8 * 9 * 768 * 32);

  dim3 g0(1024, 2, 4);
  k_prepass<<<g0, 256, 0, stream>>>(x, xbf);
  k_repack<<<6912, 256, 0, stream>>>(Wq, Wk, Wv, Wp, zp);
  k_conv<<<3072, 256, 0, stream>>>(xbf, Wp, zp, bq, bk, bv, qkv);
  k_attn<<<2048, 256, 0, stream>>>(qkv, x, out);
}